// Round 9
// baseline (374.005 us; speedup 1.0000x reference)
//
#include <hip/hip_runtime.h>
#include <hip/hip_bf16.h>

#define N_NODES 50000
#define N_EDGES 600000
#define N_GRAPHS 100
#define M_PAD 50176   // 392 * 128
#define PSTR (M_PAD * 32)  // panel stride in elements (panel = 32 cols)

typedef __bf16 bf16_t;
typedef __attribute__((ext_vector_type(8))) __bf16 bf16x8;
typedef __attribute__((ext_vector_type(2))) __bf16 bf16x2;
typedef __attribute__((ext_vector_type(4))) float f32x4;

// ---------------- degree ----------------
__global__ void degk(const int* __restrict__ dst, int* __restrict__ deg, int n) {
    int i = blockIdx.x * 256 + threadIdx.x;
    if (i < n) atomicAdd(&deg[dst[i]], 1);
}

// ---------------- scan1 + norm fused ----------------
__global__ __launch_bounds__(1024) void scan1(const int* __restrict__ deg,
                                              int* __restrict__ row_off,
                                              int* __restrict__ partial,
                                              float* __restrict__ norm, int n) {
    __shared__ int buf[1024];
    int i = blockIdx.x * 1024 + threadIdx.x;
    int v = (i < n) ? deg[i] : 0;
    if (i < n) norm[i] = rsqrtf(fmaxf((float)v, 1.0f));
    buf[threadIdx.x] = v;
    __syncthreads();
    for (int off = 1; off < 1024; off <<= 1) {
        int t = (threadIdx.x >= off) ? buf[threadIdx.x - off] : 0;
        __syncthreads();
        buf[threadIdx.x] += t;
        __syncthreads();
    }
    if (i < n) row_off[i + 1] = buf[threadIdx.x];
    if (threadIdx.x == 1023) partial[blockIdx.x] = buf[1023];
}

__global__ void scan2(int* __restrict__ partial, int nchunks) {
    int lane = threadIdx.x;
    int v = (lane < nchunks) ? partial[lane] : 0;
    for (int off = 1; off < 64; off <<= 1) {
        int t = __shfl_up(v, off, 64);
        if (lane >= off) v += t;
    }
    int ex = __shfl_up(v, 1, 64);
    if (lane == 0) ex = 0;
    if (lane < nchunks) partial[lane] = ex;
}

__global__ void scan3(int* __restrict__ row_off, const int* __restrict__ partial, int n) {
    int i = blockIdx.x * 256 + threadIdx.x;
    if (i == 0) row_off[0] = 0;
    if (i < n) row_off[i + 1] += partial[i >> 10];
}

// ---------------- CSR scatter ----------------
__global__ void scatterk(const int* __restrict__ src, const int* __restrict__ dst,
                         const int* __restrict__ row_off, int* __restrict__ cursor,
                         int* __restrict__ csr_src, int n) {
    int e = blockIdx.x * 256 + threadIdx.x;
    if (e >= n) return;
    int d = dst[e];
    int pos = atomicAdd(&cursor[d], 1);
    csr_src[row_off[d] + pos] = src[e];
}

// ---------------- prescale: xb = bf16(x), panel-major ----------------
__global__ void prescale(const float* __restrict__ x, bf16_t* __restrict__ xb, int n) {
    int i = blockIdx.x * 256 + threadIdx.x;
    if (i >= n * 64) return;
    int node = i >> 6;
    int c = (i & 63) * 2;
    float2 v = *(const float2*)(x + (size_t)node * 128 + c);
    bf16x2 vb; vb[0] = (bf16_t)v.x; vb[1] = (bf16_t)v.y;
    *(bf16x2*)(xb + (size_t)(c >> 5) * PSTR + (size_t)node * 32 + (c & 31)) = vb;
}

// ---------------- W1+W2 permute to MFMA B-fragment layout ----------------
__global__ void permWall(const float* __restrict__ W1, const float* __restrict__ W2,
                         bf16_t* __restrict__ Wp1, bf16_t* __restrict__ Wp2) {
    int i = blockIdx.x * 256 + threadIdx.x;
    const float* W; bf16_t* Wp; int N;
    if (i < 384 * 128) { W = W1; Wp = Wp1; N = 128; }
    else if (i < 384 * 128 + 384 * 64) { i -= 384 * 128; W = W2; Wp = Wp2; N = 64; }
    else return;
    int k = i / N, n = i - k * N;
    int kt = k >> 5, q = (k >> 3) & 3, j = k & 7;
    int nt = n >> 4, ln = n & 15;
    int lane = q * 16 + ln;
    Wp[(((size_t)kt * (N >> 4) + nt) * 64 + lane) * 8 + j] = (bf16_t)W[i];
}

// ---------------- SpMM, panel-major, XCD-pinned column groups ----------------
// out[d] = norm[d] * sum_s norm[s]*in[s]. Features stored as 4 contiguous
// panels of 32 cols (3.2MB each, line-disjoint). cg = blockIdx&3; with
// round-robin block->XCD dispatch, XCD k sees only panel k%4 -> per-XCD
// gather working set 3.2MB < 4MB L2, so the avg-12x row reuse becomes L2
// hits instead of LLC fabric reads (~3.3 TB/s ceiling at r4..r8). Index
// stream is nontemporal so its 2.4MB doesn't evict the panel. 4-lane
// subgroup per node: 4 x 16B = one 64B panel row; one wave instr still
// moves 16 rows x 64B = 1KB. fp32 acc, same edge order -> bitwise-stable.
__global__ __launch_bounds__(256) void spmm4(const bf16_t* __restrict__ in,
                                             bf16_t* __restrict__ out,
                                             const float* __restrict__ norm,
                                             const int* __restrict__ row_off,
                                             const int* __restrict__ csr_src, int n) {
    int cg    = blockIdx.x & 3;
    int chunk = blockIdx.x >> 2;
    int sub = threadIdx.x >> 2;   // 64 subgroups of 4 lanes
    int l   = threadIdx.x & 3;    // within-panel cols [l*8, l*8+8)
    int node = chunk * 64 + sub;
    if (node >= n) return;
    const bf16_t* panel = in + (size_t)cg * PSTR + l * 8;
    int e0 = row_off[node], e1 = row_off[node + 1];
    float acc[8] = {};
    int e = e0;
    for (; e + 8 <= e1; e += 8) {
        int s[8];
#pragma unroll
        for (int u = 0; u < 8; u++) s[u] = __builtin_nontemporal_load(csr_src + e + u);
        bf16x8 v[8];
#pragma unroll
        for (int u = 0; u < 8; u++) v[u] = *(const bf16x8*)(panel + (size_t)s[u] * 32);
        float ns[8];
#pragma unroll
        for (int u = 0; u < 8; u++) ns[u] = norm[s[u]];
#pragma unroll
        for (int u = 0; u < 8; u++)
#pragma unroll
            for (int j = 0; j < 8; j++) acc[j] += ns[u] * (float)v[u][j];
    }
    for (; e + 4 <= e1; e += 4) {
        int s[4];
#pragma unroll
        for (int u = 0; u < 4; u++) s[u] = __builtin_nontemporal_load(csr_src + e + u);
        bf16x8 v[4];
#pragma unroll
        for (int u = 0; u < 4; u++) v[u] = *(const bf16x8*)(panel + (size_t)s[u] * 32);
        float ns[4];
#pragma unroll
        for (int u = 0; u < 4; u++) ns[u] = norm[s[u]];
#pragma unroll
        for (int u = 0; u < 4; u++)
#pragma unroll
            for (int j = 0; j < 8; j++) acc[j] += ns[u] * (float)v[u][j];
    }
    for (; e < e1; e++) {
        int s = __builtin_nontemporal_load(csr_src + e);
        float ns = norm[s];
        bf16x8 v = *(const bf16x8*)(panel + (size_t)s * 32);
#pragma unroll
        for (int j = 0; j < 8; j++) acc[j] += ns * (float)v[j];
    }
    float nd = norm[node];
    bf16x8 o;
#pragma unroll
    for (int j = 0; j < 8; j++) o[j] = (bf16_t)(acc[j] * nd);
    *(bf16x8*)(out + (size_t)cg * PSTR + (size_t)node * 32 + l * 8) = o;
}

// ---------------- MFMA concat-GEMM (panel-major A): relu([f0|f1|f2] @ W + b) ----------------
template <int NT, bool BF16OUT>
__global__ __launch_bounds__(256) void gemm_mfma(const bf16_t* __restrict__ f0,
                                                 const bf16_t* __restrict__ f1,
                                                 const bf16_t* __restrict__ f2,
                                                 const bf16_t* __restrict__ Wp,
                                                 const float* __restrict__ bias,
                                                 bf16_t* __restrict__ out_b,
                                                 float* __restrict__ out_f, int M) {
    int wave = threadIdx.x >> 6;
    int lane = threadIdx.x & 63;
    int q = lane >> 4, ln = lane & 15;
    int row0 = blockIdx.x * 128 + wave * 32;

    f32x4 acc[2][NT] = {};
    const bf16_t* feats[3] = {f0, f1, f2};
    const bf16x8* Wf = (const bf16x8*)Wp;

#pragma unroll
    for (int kc = 0; kc < 12; kc++) {
        // k-chunk kc covers cols [(kc&3)*32 + q*8 .. +8) of feature (kc>>2)
        // = panel (kc&3), within-panel col q*8 (panel-major layout).
        const bf16_t* A = feats[kc >> 2] + (size_t)(kc & 3) * PSTR + q * 8;
        bf16x8 a0 = *(const bf16x8*)(A + (size_t)(row0 + ln) * 32);
        bf16x8 a1 = *(const bf16x8*)(A + (size_t)(row0 + 16 + ln) * 32);
        const bf16x8* Bp = Wf + (size_t)kc * NT * 64 + lane;
#pragma unroll
        for (int nt = 0; nt < NT; nt++) {
            bf16x8 b = Bp[nt * 64];
            acc[0][nt] = __builtin_amdgcn_mfma_f32_16x16x32_bf16(a0, b, acc[0][nt], 0, 0, 0);
            acc[1][nt] = __builtin_amdgcn_mfma_f32_16x16x32_bf16(a1, b, acc[1][nt], 0, 0, 0);
        }
    }

    float bv[NT];
#pragma unroll
    for (int nt = 0; nt < NT; nt++) bv[nt] = bias[nt * 16 + ln];

#pragma unroll
    for (int mt = 0; mt < 2; mt++) {
#pragma unroll
        for (int r = 0; r < 4; r++) {
            int row = row0 + mt * 16 + q * 4 + r;
            if (row >= M) continue;
#pragma unroll
            for (int nt = 0; nt < NT; nt++) {
                float val = fmaxf(acc[mt][nt][r] + bv[nt], 0.f);
                if (BF16OUT) {
                    // col = nt*16+ln -> panel nt>>1, within-panel (nt&1)*16+ln
                    out_b[(size_t)(nt >> 1) * PSTR + (size_t)row * 32 + (nt & 1) * 16 + ln] = (bf16_t)val;
                } else {
                    out_f[(size_t)row * 64 + nt * 16 + ln] = val;
                }
            }
        }
    }
}

// ---------------- parallel per-graph max pool ----------------
__global__ __launch_bounds__(256) void maxpool2(const float* __restrict__ hF,
                                                const int* __restrict__ gid,
                                                unsigned int* __restrict__ out, int n) {
    int wave = threadIdx.x >> 6;
    int lane = threadIdx.x & 63;
    int n0 = blockIdx.x * 256 + wave * 64;
    if (n0 >= n) return;
    int n1 = min(n0 + 64, n);
    int cur = gid[n0];
    float m = 0.f;
    int i = n0;
    for (; i + 4 <= n1; i += 4) {
        int g0 = gid[i + 0], g1 = gid[i + 1], g2 = gid[i + 2], g3 = gid[i + 3];
        float v0 = hF[(size_t)(i + 0) * 64 + lane];
        float v1 = hF[(size_t)(i + 1) * 64 + lane];
        float v2 = hF[(size_t)(i + 2) * 64 + lane];
        float v3 = hF[(size_t)(i + 3) * 64 + lane];
        if (g0 != cur) { atomicMax(&out[cur * 64 + lane], __float_as_uint(m)); cur = g0; m = v0; } else m = fmaxf(m, v0);
        if (g1 != cur) { atomicMax(&out[cur * 64 + lane], __float_as_uint(m)); cur = g1; m = v1; } else m = fmaxf(m, v1);
        if (g2 != cur) { atomicMax(&out[cur * 64 + lane], __float_as_uint(m)); cur = g2; m = v2; } else m = fmaxf(m, v2);
        if (g3 != cur) { atomicMax(&out[cur * 64 + lane], __float_as_uint(m)); cur = g3; m = v3; } else m = fmaxf(m, v3);
    }
    for (; i < n1; i++) {
        int g = gid[i];
        float v = hF[(size_t)i * 64 + lane];
        if (g != cur) { atomicMax(&out[cur * 64 + lane], __float_as_uint(m)); cur = g; m = v; }
        else m = fmaxf(m, v);
    }
    atomicMax(&out[cur * 64 + lane], __float_as_uint(m));
}

extern "C" void kernel_launch(void* const* d_in, const int* in_sizes, int n_in,
                              void* d_out, int out_size, void* d_ws, size_t ws_size,
                              hipStream_t stream) {
    const float* x  = (const float*)d_in[0];
    const float* W1 = (const float*)d_in[1];
    const float* b1 = (const float*)d_in[2];
    const float* W2 = (const float*)d_in[3];
    const float* b2 = (const float*)d_in[4];
    const int* src  = (const int*)d_in[5];
    const int* dst  = (const int*)d_in[6];
    const int* gid  = (const int*)d_in[7];
    float* out = (float*)d_out;

    char* ws = (char*)d_ws;
    size_t off = 0;
    auto take = [&](size_t bytes) {
        void* p = ws + off;
        off = (off + bytes + 255) & ~(size_t)255;
        return p;
    };
    int* deg     = (int*)take((size_t)N_NODES * 4);
    int* cursor  = (int*)take((size_t)N_NODES * 4);
    size_t zero_bytes = off;
    float* norm  = (float*)take((size_t)N_NODES * 4);
    int* row_off = (int*)take((size_t)(N_NODES + 1) * 4);
    int* partial = (int*)take(64 * 4);
    int* csr_src = (int*)take((size_t)N_EDGES * 4);
    bf16_t* Wp1  = (bf16_t*)take((size_t)384 * 128 * 2);
    bf16_t* Wp2  = (bf16_t*)take((size_t)384 * 64 * 2);
    bf16_t* B0 = (bf16_t*)take((size_t)M_PAD * 128 * 2);  // xb (panel-major)
    bf16_t* B1 = (bf16_t*)take((size_t)M_PAD * 128 * 2);  // hF (fp32, 64 cols row-major)
    bf16_t* B2 = (bf16_t*)take((size_t)M_PAD * 128 * 2);  // c1b -> d1b (panel-major)
    bf16_t* B3 = (bf16_t*)take((size_t)M_PAD * 128 * 2);  // c2b -> d2b (panel-major)
    bf16_t* B5 = (bf16_t*)take((size_t)M_PAD * 128 * 2);  // hL1b (panel-major)
    (void)ws_size; (void)in_sizes; (void)n_in; (void)out_size;

    hipMemsetAsync(d_ws, 0, zero_bytes, stream);
    hipMemsetAsync(d_out, 0, (size_t)N_GRAPHS * 64 * 4, stream);

    degk<<<(N_EDGES + 255) / 256, 256, 0, stream>>>(dst, deg, N_EDGES);

    int nchunks = (N_NODES + 1023) / 1024;
    scan1<<<nchunks, 1024, 0, stream>>>(deg, row_off, partial, norm, N_NODES);
    scan2<<<1, 64, 0, stream>>>(partial, nchunks);
    scan3<<<(N_NODES + 255) / 256, 256, 0, stream>>>(row_off, partial, N_NODES);
    scatterk<<<(N_EDGES + 255) / 256, 256, 0, stream>>>(src, dst, row_off, cursor, csr_src, N_EDGES);

    prescale<<<(N_NODES * 64 + 255) / 256, 256, 0, stream>>>(x, B0, N_NODES);
    permWall<<<(384 * 192 + 255) / 256, 256, 0, stream>>>(W1, W2, Wp1, Wp2);

    int spmm_grid = ((N_NODES + 63) / 64) * 4;  // 782 node-chunks x 4 panels
    int gemm_grid = M_PAD / 128;                // 392
    // layer 1: hops (norm folded into gather)
    spmm4<<<spmm_grid, 256, 0, stream>>>(B0, B2, norm, row_off, csr_src, N_NODES);
    spmm4<<<spmm_grid, 256, 0, stream>>>(B2, B3, norm, row_off, csr_src, N_NODES);
    // layer 1: GEMM -> hL1b (B5)
    gemm_mfma<8, true><<<gemm_grid, 256, 0, stream>>>(B0, B2, B3, Wp1, b1, B5, nullptr, N_NODES);
    // layer 2: hops
    spmm4<<<spmm_grid, 256, 0, stream>>>(B5, B2, norm, row_off, csr_src, N_NODES);
    spmm4<<<spmm_grid, 256, 0, stream>>>(B2, B3, norm, row_off, csr_src, N_NODES);
    // layer 2: GEMM -> hF (B1 as fp32, 64 cols)
    gemm_mfma<4, false><<<gemm_grid, 256, 0, stream>>>(B5, B2, B3, Wp2, b2, nullptr, (float*)B1, N_NODES);
    // readout
    maxpool2<<<(N_NODES + 255) / 256, 256, 0, stream>>>((const float*)B1, gid, (unsigned int*)out, N_NODES);
}